// Round 5
// baseline (292.537 us; speedup 1.0000x reference)
//
#include <hip/hip_runtime.h>
#include <math.h>

#define NNODES 50000
#define NEDGES 400000
#define E2 (NEDGES + NNODES)   // with self loops
#define HC 256                 // heads*channels per side
#define NOUT 512               // concat [Wl | Wr]
#define NF (NOUT / 16)         // 32 n-fragments
#define BN_SCALE 0.9999950000374997f   // 1/sqrt(1+1e-5)
#define SCAN_B ((NNODES + 255) / 256)  // 196

typedef unsigned short ushortx8 __attribute__((ext_vector_type(8)));
typedef __bf16 bf16x8 __attribute__((ext_vector_type(8)));
typedef float f32x4 __attribute__((ext_vector_type(4)));

__device__ inline unsigned short f2bf(float f) {
    unsigned u = __float_as_uint(f);
    u += 0x7fff + ((u >> 16) & 1);   // round to nearest even
    return (unsigned short)(u >> 16);
}
__device__ inline float bf2f(unsigned short u) {
    return __uint_as_float(((unsigned)u) << 16);
}

// ---------------- CSR build ----------------
__global__ void hist_dst(const int* __restrict__ ei, int* __restrict__ deg) {
    int i = blockIdx.x * blockDim.x + threadIdx.x;
    if (i >= E2) return;
    int d = (i < NEDGES) ? ei[NEDGES + i] : i - NEDGES;
    atomicAdd(&deg[d], 1);
}

__global__ __launch_bounds__(256) void scan1(const int* __restrict__ deg,
                                             int* __restrict__ rowptr,
                                             int* __restrict__ bsum) {
    int t = threadIdx.x;
    int i = blockIdx.x * 256 + t;
    int v = (i < NNODES) ? deg[i] : 0;
    __shared__ int buf[256];
    buf[t] = v;
    __syncthreads();
    for (int off = 1; off < 256; off <<= 1) {
        int u = (t >= off) ? buf[t - off] : 0;
        __syncthreads();
        buf[t] += u;
        __syncthreads();
    }
    if (i < NNODES) rowptr[i] = buf[t] - v;
    if (t == 255) bsum[blockIdx.x] = buf[255];
}

__global__ __launch_bounds__(256) void scan2(int* __restrict__ bsum,
                                             int* __restrict__ rowptr) {
    int t = threadIdx.x;
    int v = (t < SCAN_B) ? bsum[t] : 0;
    __shared__ int buf[256];
    buf[t] = v;
    __syncthreads();
    for (int off = 1; off < 256; off <<= 1) {
        int u = (t >= off) ? buf[t - off] : 0;
        __syncthreads();
        buf[t] += u;
        __syncthreads();
    }
    if (t < SCAN_B) bsum[t] = buf[t] - v;
    if (t == 0) rowptr[NNODES] = E2;
}

__global__ void scan3(int* __restrict__ rowptr, const int* __restrict__ bsum,
                      int* __restrict__ cursor) {
    int i = blockIdx.x * 256 + threadIdx.x;
    if (i >= NNODES) return;
    int r = rowptr[i] + bsum[blockIdx.x];
    rowptr[i] = r;
    cursor[i] = r;
}

__global__ void scatter_csr(const int* __restrict__ ei, int* __restrict__ cursor,
                            int* __restrict__ csr_src) {
    int i = blockIdx.x * blockDim.x + threadIdx.x;
    if (i >= E2) return;
    int s, d;
    if (i < NEDGES) { s = ei[i]; d = ei[NEDGES + i]; }
    else            { s = i - NEDGES; d = s; }
    int slot = atomicAdd(&cursor[d], 1);
    csr_src[slot] = s;
}

// ---------------- merged packing: x->bf16, W1 pack, W2 pack ----------------
__device__ inline void prep_one(const float* __restrict__ Wl, const float* __restrict__ Wr,
                                unsigned short* __restrict__ Bf, int id) {
    // Bf[(((kb*NF + nf)*64 + lane)*8 + j)] = B[kb*32 + (lane>>4)*8 + j][nf*16 + (lane&15)]
    int j    = id & 7;
    int lane = (id >> 3) & 63;
    int nf   = (id >> 9) & (NF - 1);
    int kb   = id >> 14;
    int k = kb * 32 + (lane >> 4) * 8 + j;
    int c = nf * 16 + (lane & 15);
    float v = (c < 256) ? Wl[k * 256 + c] : Wr[k * 256 + (c - 256)];
    Bf[id] = f2bf(v);
}

#define XCVT_N (NNODES * 128 / 4)   // 1,600,000 float4s
#define B1_N (128 * NOUT)           // 65,536
#define B2_N (256 * NOUT)           // 131,072

__global__ void pack_all(const float* __restrict__ x,
                         const float* __restrict__ W1l, const float* __restrict__ W1r,
                         const float* __restrict__ W2l, const float* __restrict__ W2r,
                         unsigned short* __restrict__ x_bf,
                         unsigned short* __restrict__ Bf1,
                         unsigned short* __restrict__ Bf2) {
    int id = blockIdx.x * blockDim.x + threadIdx.x;
    if (id < XCVT_N) {
        float4 v = reinterpret_cast<const float4*>(x)[id];
        ushort4 o = { f2bf(v.x), f2bf(v.y), f2bf(v.z), f2bf(v.w) };
        reinterpret_cast<ushort4*>(x_bf)[id] = o;
    } else if (id < XCVT_N + B1_N) {
        prep_one(W1l, W1r, Bf1, id - XCVT_N);
    } else if (id < XCVT_N + B1_N + B2_N) {
        prep_one(W2l, W2r, Bf2, id - XCVT_N - B1_N);
    }
}

// ---------------- bf16 MFMA GEMM: C[M][512] = A[M][K] * B[K][512], C in bf16 ----------------
__global__ __launch_bounds__(256) void gemm_mfma(
        const unsigned short* __restrict__ A,   // bf16 [M][K]
        const unsigned short* __restrict__ Bf,  // fragment-ready bf16
        unsigned short* __restrict__ C,         // bf16 [M][512]
        int M, int K) {
    const int tid  = threadIdx.x;
    const int lane = tid & 63;
    const int w    = tid >> 6;          // col panel 0..3
    const int row0 = blockIdx.x * 64;
    const int col0 = w * 128;
    const int lr = lane & 15, lg = lane >> 4;

    f32x4 acc[4][8] = {};
    const int nkb = K >> 5;
    for (int kb = 0; kb < nkb; ++kb) {
        bf16x8 af[4], bfr[8];
        const int kcol = kb * 32 + lg * 8;
#pragma unroll
        for (int i = 0; i < 4; ++i) {
            int r = row0 + i * 16 + lr;
            ushortx8 av = {};
            if (r < M)
                av = *reinterpret_cast<const ushortx8*>(A + (size_t)r * K + kcol);
            af[i] = __builtin_bit_cast(bf16x8, av);
        }
#pragma unroll
        for (int j = 0; j < 8; ++j) {
            int nf = (col0 >> 4) + j;
            ushortx8 bv = *reinterpret_cast<const ushortx8*>(
                Bf + (((size_t)(kb * NF + nf) * 64 + lane) << 3));
            bfr[j] = __builtin_bit_cast(bf16x8, bv);
        }
#pragma unroll
        for (int i = 0; i < 4; ++i)
#pragma unroll
            for (int j = 0; j < 8; ++j)
                acc[i][j] = __builtin_amdgcn_mfma_f32_16x16x32_bf16(
                    af[i], bfr[j], acc[i][j], 0, 0, 0);
    }
#pragma unroll
    for (int i = 0; i < 4; ++i) {
#pragma unroll
        for (int r = 0; r < 4; ++r) {
            int row = row0 + i * 16 + lg * 4 + r;
            if (row < M) {
#pragma unroll
                for (int j = 0; j < 8; ++j)
                    C[(size_t)row * NOUT + col0 + j * 16 + lr] = f2bf(acc[i][j][r]);
            }
        }
    }
}

// ---------------- fused per-node GAT: 2 edges/wave-iter, 8 ch/lane ----------------
// xlr[N][512] bf16: cols 0..255 = xl (messages), 256..511 = xr (dest)
// lane = half*32 + sub; half = which edge of the pair, sub covers cols [8*sub, 8*sub+8)
// head of a column c (c<256) = c>>6; a lane's 8 cols stay within one head.
// LAYER==1: out = bf16 h1[N][256] = ELU(BN(agg + b))
// LAYER==2: out = fp32 [N] = sigmoid(fc(ELU(BN(mean_heads(agg) + b))))
template <int LAYER>
__global__ __launch_bounds__(256) void gat_node(
        const unsigned short* __restrict__ xlr,
        const float* __restrict__ att, const int* __restrict__ rowptr,
        const int* __restrict__ csr_src,
        const float* __restrict__ bias, const float* __restrict__ g,
        const float* __restrict__ be,
        const float* __restrict__ fcW, const float* __restrict__ fcb,
        void* __restrict__ outv) {
    int wid  = (blockIdx.x * blockDim.x + threadIdx.x) >> 6;   // node id
    int lane = threadIdx.x & 63;
    if (wid >= NNODES) return;
    const int half = lane >> 5;
    const int sub  = lane & 31;
    const int c0   = sub * 8;

    // hoisted: dest features xr[wid] (8 ch) and att (8 ch)
    float xb[8], atv[8];
    {
        ushortx8 xbv = *reinterpret_cast<const ushortx8*>(xlr + (size_t)wid * NOUT + 256 + c0);
#pragma unroll
        for (int k = 0; k < 8; ++k) xb[k] = bf2f(xbv[k]);
        float4 a0 = *reinterpret_cast<const float4*>(att + c0);
        float4 a1 = *reinterpret_cast<const float4*>(att + c0 + 4);
        atv[0] = a0.x; atv[1] = a0.y; atv[2] = a0.z; atv[3] = a0.w;
        atv[4] = a1.x; atv[5] = a1.y; atv[6] = a1.z; atv[7] = a1.w;
    }
    const int beg = rowptr[wid];
    const int end = rowptr[wid + 1];

    float den = 0.f;
    float ac[8] = {};
    for (int j = beg; j < end; j += 2) {
        int jj = j + half;
        bool valid = (jj < end);
        int s = csr_src[valid ? jj : beg];
        ushortx8 xav = *reinterpret_cast<const ushortx8*>(xlr + (size_t)s * NOUT + c0);
        float xv[8];
#pragma unroll
        for (int k = 0; k < 8; ++k) xv[k] = bf2f(xav[k]);
        float pa = 0.f, pb = 0.f;
#pragma unroll
        for (int k = 0; k < 4; ++k) {
            float v = xv[k] + xb[k];
            v = fmaxf(v, 0.2f * v);          // leaky_relu (slope 0.2)
            pa = fmaf(v, atv[k], pa);
        }
#pragma unroll
        for (int k = 4; k < 8; ++k) {
            float v = xv[k] + xb[k];
            v = fmaxf(v, 0.2f * v);
            pb = fmaf(v, atv[k], pb);
        }
        float part = pa + pb;
        // per-head logit: sum over the 8 lanes of this head (offsets 1,2,4)
        part += __shfl_xor(part, 1);
        part += __shfl_xor(part, 2);
        part += __shfl_xor(part, 4);
        // softmax shift-invariant; logits are O(1) -> no max tracking
        float p = valid ? __expf(part) : 0.f;
        den += p;
#pragma unroll
        for (int k = 0; k < 8; ++k) ac[k] = fmaf(p, xv[k], ac[k]);
    }
    // merge the two half-wave edge groups
    den += __shfl_xor(den, 32);
#pragma unroll
    for (int k = 0; k < 8; ++k) ac[k] += __shfl_xor(ac[k], 32);
    float inv = 1.f / (den + 1e-16f);
#pragma unroll
    for (int k = 0; k < 8; ++k) ac[k] *= inv;

    if (LAYER == 1) {
        if (half == 0) {
            float4 b0 = *reinterpret_cast<const float4*>(bias + c0);
            float4 b1 = *reinterpret_cast<const float4*>(bias + c0 + 4);
            float4 g0 = *reinterpret_cast<const float4*>(g + c0);
            float4 g1 = *reinterpret_cast<const float4*>(g + c0 + 4);
            float4 e0 = *reinterpret_cast<const float4*>(be + c0);
            float4 e1 = *reinterpret_cast<const float4*>(be + c0 + 4);
            float bs[8] = { b0.x, b0.y, b0.z, b0.w, b1.x, b1.y, b1.z, b1.w };
            float gg[8] = { g0.x, g0.y, g0.z, g0.w, g1.x, g1.y, g1.z, g1.w };
            float ee[8] = { e0.x, e0.y, e0.z, e0.w, e1.x, e1.y, e1.z, e1.w };
            ushortx8 ov;
#pragma unroll
            for (int k = 0; k < 8; ++k) {
                float v = (ac[k] + bs[k]) * BN_SCALE * gg[k] + ee[k];
                v = v > 0.f ? v : expm1f(v);
                ov[k] = f2bf(v);
            }
            *reinterpret_cast<ushortx8*>((unsigned short*)outv + (size_t)wid * HC + c0) = ov;
        }
    } else {
        // mean over heads: lanes sub, sub^8, sub^16(, sub^24) share a channel
#pragma unroll
        for (int k = 0; k < 8; ++k) {
            ac[k] += __shfl_xor(ac[k], 8);
            ac[k] += __shfl_xor(ac[k], 16);
        }
        int cc = (sub & 7) * 8;
        float dot = 0.f;
#pragma unroll
        for (int k = 0; k < 8; ++k) {
            float v = (ac[k] * 0.25f + bias[cc + k]) * BN_SCALE * g[cc + k] + be[cc + k];
            v = v > 0.f ? v : expm1f(v);
            dot = fmaf(v, fcW[cc + k], dot);
        }
        dot += __shfl_xor(dot, 1);
        dot += __shfl_xor(dot, 2);
        dot += __shfl_xor(dot, 4);
        if (lane == 0) ((float*)outv)[wid] = 1.f / (1.f + __expf(-(dot + fcb[0])));
    }
}

extern "C" void kernel_launch(void* const* d_in, const int* in_sizes, int n_in,
                              void* d_out, int out_size, void* d_ws, size_t ws_size,
                              hipStream_t stream) {
    const float* x    = (const float*)d_in[0];
    const int*   ei   = (const int*)d_in[1];
    const float* W1l  = (const float*)d_in[2];
    const float* W1r  = (const float*)d_in[3];
    const float* att1 = (const float*)d_in[4];
    const float* b1   = (const float*)d_in[5];
    const float* g1   = (const float*)d_in[6];
    const float* be1  = (const float*)d_in[7];
    const float* W2l  = (const float*)d_in[8];
    const float* W2r  = (const float*)d_in[9];
    const float* att2 = (const float*)d_in[10];
    const float* b2   = (const float*)d_in[11];
    const float* g2   = (const float*)d_in[12];
    const float* be2  = (const float*)d_in[13];
    const float* fcW  = (const float*)d_in[14];
    const float* fcb  = (const float*)d_in[15];
    float* out = (float*)d_out;

    // workspace carve-up (bf16 = ushort)
    unsigned short* xlr   = (unsigned short*)d_ws;                 // N*512
    unsigned short* x_bf  = xlr + (size_t)NNODES * NOUT;           // N*128
    unsigned short* h1_bf = x_bf + (size_t)NNODES * 128;           // N*256
    unsigned short* Bf1   = h1_bf + (size_t)NNODES * 256;          // 128*512
    unsigned short* Bf2   = Bf1 + 128 * NOUT;                      // 256*512
    int* csr_src = (int*)(Bf2 + 256 * NOUT);                       // E2
    int* deg     = csr_src + E2;                                   // N
    int* rowptr  = deg + NNODES;                                   // N+1
    int* cursor  = rowptr + NNODES + 1;                            // N
    int* bsum    = cursor + NNODES;                                // SCAN_B

    const int edgeBlocks = (E2 + 255) / 256;
    const int nodeBlocks = (NNODES * 64 + 255) / 256;
    const int gemmGrid   = (NNODES + 63) / 64;
    const int packBlocks = (XCVT_N + B1_N + B2_N + 255) / 256;

    // ---- CSR build ----
    hipMemsetAsync(deg, 0, NNODES * sizeof(int), stream);
    hist_dst<<<edgeBlocks, 256, 0, stream>>>(ei, deg);
    scan1<<<SCAN_B, 256, 0, stream>>>(deg, rowptr, bsum);
    scan2<<<1, 256, 0, stream>>>(bsum, rowptr);
    scan3<<<SCAN_B, 256, 0, stream>>>(rowptr, bsum, cursor);
    scatter_csr<<<edgeBlocks, 256, 0, stream>>>(ei, cursor, csr_src);

    // ---- packing (x -> bf16, W1/W2 -> fragment layout) ----
    pack_all<<<packBlocks, 256, 0, stream>>>(x, W1l, W1r, W2l, W2r, x_bf, Bf1, Bf2);

    // ---- layer 1 ----
    gemm_mfma<<<gemmGrid, 256, 0, stream>>>(x_bf, Bf1, xlr, NNODES, 128);
    gat_node<1><<<nodeBlocks, 256, 0, stream>>>(xlr, att1, rowptr, csr_src,
                                                b1, g1, be1, nullptr, nullptr, h1_bf);

    // ---- layer 2 ----
    gemm_mfma<<<gemmGrid, 256, 0, stream>>>(h1_bf, Bf2, xlr, NNODES, 256);
    gat_node<2><<<nodeBlocks, 256, 0, stream>>>(xlr, att2, rowptr, csr_src,
                                                b2, g2, be2, fcW, fcb, out);
}

// Round 6
// 232.911 us; speedup vs baseline: 1.2560x; 1.2560x over previous
//
#include <hip/hip_runtime.h>
#include <math.h>

#define NNODES 50000
#define NEDGES 400000
#define E2 (NEDGES + NNODES)   // with self loops
#define HC 256                 // heads*channels per side
#define NOUT 512               // concat [Wl | Wr]
#define NF (NOUT / 16)         // 32 n-fragments
#define BN_SCALE 0.9999950000374997f   // 1/sqrt(1+1e-5)
#define SCAN_B ((NNODES + 255) / 256)  // 196

typedef unsigned short ushortx8 __attribute__((ext_vector_type(8)));
typedef __bf16 bf16x8 __attribute__((ext_vector_type(8)));
typedef float f32x4 __attribute__((ext_vector_type(4)));
typedef float f32x2 __attribute__((ext_vector_type(2)));

__device__ inline unsigned short f2bf(float f) {
    unsigned u = __float_as_uint(f);
    u += 0x7fff + ((u >> 16) & 1);   // round to nearest even
    return (unsigned short)(u >> 16);
}
__device__ inline float bf2f(unsigned short u) {
    return __uint_as_float(((unsigned)u) << 16);
}

// ---------------- CSR build ----------------
__global__ void hist_dst(const int* __restrict__ ei, int* __restrict__ deg) {
    int i = blockIdx.x * blockDim.x + threadIdx.x;
    if (i >= E2) return;
    int d = (i < NEDGES) ? ei[NEDGES + i] : i - NEDGES;
    atomicAdd(&deg[d], 1);
}

__global__ __launch_bounds__(256) void scan1(const int* __restrict__ deg,
                                             int* __restrict__ rowptr,
                                             int* __restrict__ bsum) {
    int t = threadIdx.x;
    int i = blockIdx.x * 256 + t;
    int v = (i < NNODES) ? deg[i] : 0;
    __shared__ int buf[256];
    buf[t] = v;
    __syncthreads();
    for (int off = 1; off < 256; off <<= 1) {
        int u = (t >= off) ? buf[t - off] : 0;
        __syncthreads();
        buf[t] += u;
        __syncthreads();
    }
    if (i < NNODES) rowptr[i] = buf[t] - v;
    if (t == 255) bsum[blockIdx.x] = buf[255];
}

__global__ __launch_bounds__(256) void scan2(int* __restrict__ bsum,
                                             int* __restrict__ rowptr) {
    int t = threadIdx.x;
    int v = (t < SCAN_B) ? bsum[t] : 0;
    __shared__ int buf[256];
    buf[t] = v;
    __syncthreads();
    for (int off = 1; off < 256; off <<= 1) {
        int u = (t >= off) ? buf[t - off] : 0;
        __syncthreads();
        buf[t] += u;
        __syncthreads();
    }
    if (t < SCAN_B) bsum[t] = buf[t] - v;
    if (t == 0) rowptr[NNODES] = E2;
}

__global__ void scan3(int* __restrict__ rowptr, const int* __restrict__ bsum,
                      int* __restrict__ cursor) {
    int i = blockIdx.x * 256 + threadIdx.x;
    if (i >= NNODES) return;
    int r = rowptr[i] + bsum[blockIdx.x];
    rowptr[i] = r;
    cursor[i] = r;
}

__global__ void scatter_csr(const int* __restrict__ ei, int* __restrict__ cursor,
                            int* __restrict__ csr_src) {
    int i = blockIdx.x * blockDim.x + threadIdx.x;
    if (i >= E2) return;
    int s, d;
    if (i < NEDGES) { s = ei[i]; d = ei[NEDGES + i]; }
    else            { s = i - NEDGES; d = s; }
    int slot = atomicAdd(&cursor[d], 1);
    csr_src[slot] = s;
}

// ---------------- merged packing: x->bf16, W1 pack, W2 pack ----------------
__device__ inline void prep_one(const float* __restrict__ Wl, const float* __restrict__ Wr,
                                unsigned short* __restrict__ Bf, int id) {
    // Bf[(((kb*NF + nf)*64 + lane)*8 + j)] = B[kb*32 + (lane>>4)*8 + j][nf*16 + (lane&15)]
    int j    = id & 7;
    int lane = (id >> 3) & 63;
    int nf   = (id >> 9) & (NF - 1);
    int kb   = id >> 14;
    int k = kb * 32 + (lane >> 4) * 8 + j;
    int c = nf * 16 + (lane & 15);
    float v = (c < 256) ? Wl[k * 256 + c] : Wr[k * 256 + (c - 256)];
    Bf[id] = f2bf(v);
}

#define XCVT_N (NNODES * 128 / 4)   // 1,600,000 float4s
#define B1_N (128 * NOUT)           // 65,536
#define B2_N (256 * NOUT)           // 131,072

__global__ void pack_all(const float* __restrict__ x,
                         const float* __restrict__ W1l, const float* __restrict__ W1r,
                         const float* __restrict__ W2l, const float* __restrict__ W2r,
                         unsigned short* __restrict__ x_bf,
                         unsigned short* __restrict__ Bf1,
                         unsigned short* __restrict__ Bf2) {
    int id = blockIdx.x * blockDim.x + threadIdx.x;
    if (id < XCVT_N) {
        float4 v = reinterpret_cast<const float4*>(x)[id];
        ushort4 o = { f2bf(v.x), f2bf(v.y), f2bf(v.z), f2bf(v.w) };
        reinterpret_cast<ushort4*>(x_bf)[id] = o;
    } else if (id < XCVT_N + B1_N) {
        prep_one(W1l, W1r, Bf1, id - XCVT_N);
    } else if (id < XCVT_N + B1_N + B2_N) {
        prep_one(W2l, W2r, Bf2, id - XCVT_N - B1_N);
    }
}

// ---------------- bf16 MFMA GEMM: C[M][512] = A[M][K] * B[K][512], C in bf16 ----------------
__global__ __launch_bounds__(256) void gemm_mfma(
        const unsigned short* __restrict__ A,   // bf16 [M][K]
        const unsigned short* __restrict__ Bf,  // fragment-ready bf16
        unsigned short* __restrict__ C,         // bf16 [M][512]
        int M, int K) {
    const int tid  = threadIdx.x;
    const int lane = tid & 63;
    const int w    = tid >> 6;          // col panel 0..3
    const int row0 = blockIdx.x * 64;
    const int col0 = w * 128;
    const int lr = lane & 15, lg = lane >> 4;

    f32x4 acc[4][8] = {};
    const int nkb = K >> 5;
    for (int kb = 0; kb < nkb; ++kb) {
        bf16x8 af[4], bfr[8];
        const int kcol = kb * 32 + lg * 8;
#pragma unroll
        for (int i = 0; i < 4; ++i) {
            int r = row0 + i * 16 + lr;
            ushortx8 av = {};
            if (r < M)
                av = *reinterpret_cast<const ushortx8*>(A + (size_t)r * K + kcol);
            af[i] = __builtin_bit_cast(bf16x8, av);
        }
#pragma unroll
        for (int j = 0; j < 8; ++j) {
            int nf = (col0 >> 4) + j;
            ushortx8 bv = *reinterpret_cast<const ushortx8*>(
                Bf + (((size_t)(kb * NF + nf) * 64 + lane) << 3));
            bfr[j] = __builtin_bit_cast(bf16x8, bv);
        }
#pragma unroll
        for (int i = 0; i < 4; ++i)
#pragma unroll
            for (int j = 0; j < 8; ++j)
                acc[i][j] = __builtin_amdgcn_mfma_f32_16x16x32_bf16(
                    af[i], bfr[j], acc[i][j], 0, 0, 0);
    }
#pragma unroll
    for (int i = 0; i < 4; ++i) {
#pragma unroll
        for (int r = 0; r < 4; ++r) {
            int row = row0 + i * 16 + lg * 4 + r;
            if (row < M) {
#pragma unroll
                for (int j = 0; j < 8; ++j)
                    C[(size_t)row * NOUT + col0 + j * 16 + lr] = f2bf(acc[i][j][r]);
            }
        }
    }
}

// ---------------- fused per-node GAT: 1 edge/iter, 4 ch/lane, packed-f32 math ----------------
// xlr[N][512] bf16: cols 0..255 = xl (messages), 256..511 = xr (dest)
// lane covers channels [4*lane, 4*lane+4); head = lane>>4; 16-lane logit reduce.
// LAYER==1: out = bf16 h1[N][256] = ELU(BN(agg + b))
// LAYER==2: out = fp32 [N] = sigmoid(fc(ELU(BN(mean_heads(agg) + b))))
template <int LAYER>
__global__ __launch_bounds__(256) void gat_node(
        const unsigned short* __restrict__ xlr,
        const float* __restrict__ att, const int* __restrict__ rowptr,
        const int* __restrict__ csr_src,
        const float* __restrict__ bias, const float* __restrict__ g,
        const float* __restrict__ be,
        const float* __restrict__ fcW, const float* __restrict__ fcb,
        void* __restrict__ outv) {
    int wid  = (blockIdx.x * blockDim.x + threadIdx.x) >> 6;   // node id
    int lane = threadIdx.x & 63;
    if (wid >= NNODES) return;

    // hoisted: dest features xr[wid] (4 ch) and att (4 ch), as float2 pairs
    f32x2 xb01, xb23, at01, at23;
    {
        uint2 wv = *reinterpret_cast<const uint2*>(xlr + (size_t)wid * NOUT + 256 + lane * 4);
        xb01.x = __uint_as_float(wv.x << 16);
        xb01.y = __uint_as_float(wv.x & 0xffff0000u);
        xb23.x = __uint_as_float(wv.y << 16);
        xb23.y = __uint_as_float(wv.y & 0xffff0000u);
        float4 a = *reinterpret_cast<const float4*>(att + lane * 4);
        at01.x = a.x; at01.y = a.y;
        at23.x = a.z; at23.y = a.w;
    }
    const int beg = rowptr[wid];
    const int end = rowptr[wid + 1];
    const unsigned short* __restrict__ xbase = xlr + lane * 4;

    float den = 0.f;
    f32x2 ac01 = {0.f, 0.f}, ac23 = {0.f, 0.f};

    // per-edge compute on packed float2 lanes (v_pk_* on CDNA)
    auto edge = [&](uint2 wv) {
        f32x2 xv01, xv23;
        xv01.x = __uint_as_float(wv.x << 16);
        xv01.y = __uint_as_float(wv.x & 0xffff0000u);
        xv23.x = __uint_as_float(wv.y << 16);
        xv23.y = __uint_as_float(wv.y & 0xffff0000u);
        f32x2 v01 = xv01 + xb01;
        f32x2 v23 = xv23 + xb23;
        v01 = __builtin_elementwise_max(v01, v01 * 0.2f);   // leaky_relu
        v23 = __builtin_elementwise_max(v23, v23 * 0.2f);
        f32x2 d2 = v01 * at01 + v23 * at23;
        float part = d2.x + d2.y;
        part += __shfl_xor(part, 1);
        part += __shfl_xor(part, 2);
        part += __shfl_xor(part, 4);
        part += __shfl_xor(part, 8);
        // softmax shift-invariant; logits are O(1) -> no max tracking
        float p = __expf(part);
        den += p;
        ac01 += p * xv01;
        ac23 += p * xv23;
    };

    int j = beg;
    for (; j + 2 <= end; j += 2) {
        int s0 = csr_src[j];
        int s1 = csr_src[j + 1];
        uint2 w0 = *reinterpret_cast<const uint2*>(xbase + (size_t)s0 * NOUT);
        uint2 w1 = *reinterpret_cast<const uint2*>(xbase + (size_t)s1 * NOUT);
        edge(w0);
        edge(w1);
    }
    if (j < end) {
        int s0 = csr_src[j];
        uint2 w0 = *reinterpret_cast<const uint2*>(xbase + (size_t)s0 * NOUT);
        edge(w0);
    }

    float inv = 1.f / (den + 1e-16f);
    float ax = ac01.x * inv, ay = ac01.y * inv, az = ac23.x * inv, aw = ac23.y * inv;

    if (LAYER == 1) {
        int c0 = lane * 4;
        float o0 = (ax + bias[c0 + 0]) * BN_SCALE * g[c0 + 0] + be[c0 + 0];
        float o1 = (ay + bias[c0 + 1]) * BN_SCALE * g[c0 + 1] + be[c0 + 1];
        float o2 = (az + bias[c0 + 2]) * BN_SCALE * g[c0 + 2] + be[c0 + 2];
        float o3 = (aw + bias[c0 + 3]) * BN_SCALE * g[c0 + 3] + be[c0 + 3];
        o0 = o0 > 0.f ? o0 : expm1f(o0);
        o1 = o1 > 0.f ? o1 : expm1f(o1);
        o2 = o2 > 0.f ? o2 : expm1f(o2);
        o3 = o3 > 0.f ? o3 : expm1f(o3);
        ushort4 o = { f2bf(o0), f2bf(o1), f2bf(o2), f2bf(o3) };
        *reinterpret_cast<ushort4*>((unsigned short*)outv + (size_t)wid * HC + lane * 4) = o;
    } else {
        // mean over heads: lanes l, l^16, l^32, l^48 hold the same channels
#pragma unroll
        for (int off = 16; off < 64; off <<= 1) {
            ax += __shfl_xor(ax, off);
            ay += __shfl_xor(ay, off);
            az += __shfl_xor(az, off);
            aw += __shfl_xor(aw, off);
        }
        int c0 = (lane & 15) * 4;
        float v0 = (ax * 0.25f + bias[c0 + 0]) * BN_SCALE * g[c0 + 0] + be[c0 + 0];
        float v1 = (ay * 0.25f + bias[c0 + 1]) * BN_SCALE * g[c0 + 1] + be[c0 + 1];
        float v2 = (az * 0.25f + bias[c0 + 2]) * BN_SCALE * g[c0 + 2] + be[c0 + 2];
        float v3 = (aw * 0.25f + bias[c0 + 3]) * BN_SCALE * g[c0 + 3] + be[c0 + 3];
        v0 = v0 > 0.f ? v0 : expm1f(v0);
        v1 = v1 > 0.f ? v1 : expm1f(v1);
        v2 = v2 > 0.f ? v2 : expm1f(v2);
        v3 = v3 > 0.f ? v3 : expm1f(v3);
        float dot = v0 * fcW[c0] + v1 * fcW[c0 + 1] + v2 * fcW[c0 + 2] + v3 * fcW[c0 + 3];
#pragma unroll
        for (int off = 8; off; off >>= 1) dot += __shfl_xor(dot, off);
        if (lane == 0) ((float*)outv)[wid] = 1.f / (1.f + __expf(-(dot + fcb[0])));
    }
}

extern "C" void kernel_launch(void* const* d_in, const int* in_sizes, int n_in,
                              void* d_out, int out_size, void* d_ws, size_t ws_size,
                              hipStream_t stream) {
    const float* x    = (const float*)d_in[0];
    const int*   ei   = (const int*)d_in[1];
    const float* W1l  = (const float*)d_in[2];
    const float* W1r  = (const float*)d_in[3];
    const float* att1 = (const float*)d_in[4];
    const float* b1   = (const float*)d_in[5];
    const float* g1   = (const float*)d_in[6];
    const float* be1  = (const float*)d_in[7];
    const float* W2l  = (const float*)d_in[8];
    const float* W2r  = (const float*)d_in[9];
    const float* att2 = (const float*)d_in[10];
    const float* b2   = (const float*)d_in[11];
    const float* g2   = (const float*)d_in[12];
    const float* be2  = (const float*)d_in[13];
    const float* fcW  = (const float*)d_in[14];
    const float* fcb  = (const float*)d_in[15];
    float* out = (float*)d_out;

    // workspace carve-up (bf16 = ushort)
    unsigned short* xlr   = (unsigned short*)d_ws;                 // N*512
    unsigned short* x_bf  = xlr + (size_t)NNODES * NOUT;           // N*128
    unsigned short* h1_bf = x_bf + (size_t)NNODES * 128;           // N*256
    unsigned short* Bf1   = h1_bf + (size_t)NNODES * 256;          // 128*512
    unsigned short* Bf2   = Bf1 + 128 * NOUT;                      // 256*512
    int* csr_src = (int*)(Bf2 + 256 * NOUT);                       // E2
    int* deg     = csr_src + E2;                                   // N
    int* rowptr  = deg + NNODES;                                   // N+1
    int* cursor  = rowptr + NNODES + 1;                            // N
    int* bsum    = cursor + NNODES;                                // SCAN_B

    const int edgeBlocks = (E2 + 255) / 256;
    const int nodeBlocks = (NNODES * 64 + 255) / 256;
    const int gemmGrid   = (NNODES + 63) / 64;
    const int packBlocks = (XCVT_N + B1_N + B2_N + 255) / 256;

    // ---- CSR build ----
    hipMemsetAsync(deg, 0, NNODES * sizeof(int), stream);
    hist_dst<<<edgeBlocks, 256, 0, stream>>>(ei, deg);
    scan1<<<SCAN_B, 256, 0, stream>>>(deg, rowptr, bsum);
    scan2<<<1, 256, 0, stream>>>(bsum, rowptr);
    scan3<<<SCAN_B, 256, 0, stream>>>(rowptr, bsum, cursor);
    scatter_csr<<<edgeBlocks, 256, 0, stream>>>(ei, cursor, csr_src);

    // ---- packing (x -> bf16, W1/W2 -> fragment layout) ----
    pack_all<<<packBlocks, 256, 0, stream>>>(x, W1l, W1r, W2l, W2r, x_bf, Bf1, Bf2);

    // ---- layer 1 ----
    gemm_mfma<<<gemmGrid, 256, 0, stream>>>(x_bf, Bf1, xlr, NNODES, 128);
    gat_node<1><<<nodeBlocks, 256, 0, stream>>>(xlr, att1, rowptr, csr_src,
                                                b1, g1, be1, nullptr, nullptr, h1_bf);

    // ---- layer 2 ----
    gemm_mfma<<<gemmGrid, 256, 0, stream>>>(h1_bf, Bf2, xlr, NNODES, 256);
    gat_node<2><<<nodeBlocks, 256, 0, stream>>>(xlr, att2, rowptr, csr_src,
                                                b2, g2, be2, fcW, fcb, out);
}

// Round 7
// 208.896 us; speedup vs baseline: 1.4004x; 1.1150x over previous
//
#include <hip/hip_runtime.h>
#include <math.h>

#define NNODES 50000
#define NEDGES 400000
#define E2 (NEDGES + NNODES)   // with self loops
#define HC 256                 // heads*channels per side
#define NOUT 512               // concat [Wl | Wr]
#define NF (NOUT / 16)         // 32 n-fragments
#define BN_SCALE 0.9999950000374997f   // 1/sqrt(1+1e-5)
#define SCAN_B ((NNODES + 255) / 256)  // 196
#define GEMM_B ((NNODES + 63) / 64)    // 782
#define HIST_B ((E2 + 255) / 256)      // 1758

typedef unsigned short ushortx8 __attribute__((ext_vector_type(8)));
typedef __bf16 bf16x8 __attribute__((ext_vector_type(8)));
typedef float f32x4 __attribute__((ext_vector_type(4)));
typedef float f32x2 __attribute__((ext_vector_type(2)));

__device__ inline unsigned short f2bf(float f) {
    unsigned u = __float_as_uint(f);
    u += 0x7fff + ((u >> 16) & 1);   // round to nearest even
    return (unsigned short)(u >> 16);
}

// VALU cross-lane add via DPP (within 16-lane row): ctrl 0xB1=xor1, 0x4E=xor2,
// 0x141=row_half_mirror (combines quads), 0x140=row_mirror (combines halves)
template <int CTRL>
__device__ __forceinline__ float dpp_add(float x) {
    int y = __builtin_amdgcn_update_dpp(0, __float_as_int(x), CTRL, 0xF, 0xF, true);
    return x + __int_as_float(y);
}
__device__ __forceinline__ float row16_sum(float x) {
    x = dpp_add<0xB1>(x);
    x = dpp_add<0x4E>(x);
    x = dpp_add<0x141>(x);
    x = dpp_add<0x140>(x);
    return x;
}

// ---------------- packing bodies ----------------
#define XCVT_N (NNODES * 128 / 4)   // 1,600,000 float4s
#define B1_N (128 * NOUT)           // 65,536
#define B2_N (256 * NOUT)           // 131,072
#define PACK_B ((XCVT_N + B1_N + B2_N + 255) / 256)

__device__ __forceinline__ void prep_one(const float* __restrict__ Wl,
                                         const float* __restrict__ Wr,
                                         unsigned short* __restrict__ Bf, int id) {
    // Bf[(((kb*NF + nf)*64 + lane)*8 + j)] = B[kb*32 + (lane>>4)*8 + j][nf*16 + (lane&15)]
    int j    = id & 7;
    int lane = (id >> 3) & 63;
    int nf   = (id >> 9) & (NF - 1);
    int kb   = id >> 14;
    int k = kb * 32 + (lane >> 4) * 8 + j;
    int c = nf * 16 + (lane & 15);
    float v = (c < 256) ? Wl[k * 256 + c] : Wr[k * 256 + (c - 256)];
    Bf[id] = f2bf(v);
}

// K1: pack (x->bf16, W1/W2 fragment layout) || dst histogram
__global__ __launch_bounds__(256) void k1_pack_hist(
        const float* __restrict__ x,
        const float* __restrict__ W1l, const float* __restrict__ W1r,
        const float* __restrict__ W2l, const float* __restrict__ W2r,
        unsigned short* __restrict__ x_bf,
        unsigned short* __restrict__ Bf1, unsigned short* __restrict__ Bf2,
        const int* __restrict__ ei, int* __restrict__ deg) {
    int bid = blockIdx.x;
    if (bid < PACK_B) {
        int id = bid * 256 + threadIdx.x;
        if (id < XCVT_N) {
            float4 v = reinterpret_cast<const float4*>(x)[id];
            ushort4 o = { f2bf(v.x), f2bf(v.y), f2bf(v.z), f2bf(v.w) };
            reinterpret_cast<ushort4*>(x_bf)[id] = o;
        } else if (id < XCVT_N + B1_N) {
            prep_one(W1l, W1r, Bf1, id - XCVT_N);
        } else if (id < XCVT_N + B1_N + B2_N) {
            prep_one(W2l, W2r, Bf2, id - XCVT_N - B1_N);
        }
    } else {
        int i = (bid - PACK_B) * 256 + threadIdx.x;
        if (i < E2) {
            int d = (i < NEDGES) ? ei[NEDGES + i] : i - NEDGES;
            atomicAdd(&deg[d], 1);
        }
    }
}

// ---------------- GEMM body: C[M][512] = A[M][K] * B[K][512], C in bf16 ----------------
__device__ __forceinline__ void gemm_body(int bx, int tid,
        const unsigned short* __restrict__ A, const unsigned short* __restrict__ Bf,
        unsigned short* __restrict__ C, int M, int K) {
    const int lane = tid & 63;
    const int w    = tid >> 6;          // col panel 0..3
    const int row0 = bx * 64;
    const int col0 = w * 128;
    const int lr = lane & 15, lg = lane >> 4;

    f32x4 acc[4][8] = {};
    const int nkb = K >> 5;
    for (int kb = 0; kb < nkb; ++kb) {
        bf16x8 af[4], bfr[8];
        const int kcol = kb * 32 + lg * 8;
#pragma unroll
        for (int i = 0; i < 4; ++i) {
            int r = row0 + i * 16 + lr;
            ushortx8 av = {};
            if (r < M)
                av = *reinterpret_cast<const ushortx8*>(A + (size_t)r * K + kcol);
            af[i] = __builtin_bit_cast(bf16x8, av);
        }
#pragma unroll
        for (int j = 0; j < 8; ++j) {
            int nf = (col0 >> 4) + j;
            ushortx8 bv = *reinterpret_cast<const ushortx8*>(
                Bf + (((size_t)(kb * NF + nf) * 64 + lane) << 3));
            bfr[j] = __builtin_bit_cast(bf16x8, bv);
        }
#pragma unroll
        for (int i = 0; i < 4; ++i)
#pragma unroll
            for (int j = 0; j < 8; ++j)
                acc[i][j] = __builtin_amdgcn_mfma_f32_16x16x32_bf16(
                    af[i], bfr[j], acc[i][j], 0, 0, 0);
    }
#pragma unroll
    for (int i = 0; i < 4; ++i) {
#pragma unroll
        for (int r = 0; r < 4; ++r) {
            int row = row0 + i * 16 + lg * 4 + r;
            if (row < M) {
#pragma unroll
                for (int j = 0; j < 8; ++j)
                    C[(size_t)row * NOUT + col0 + j * 16 + lr] = f2bf(acc[i][j][r]);
            }
        }
    }
}

// K2: gemm layer-1 || block-local exclusive scan of deg
__global__ __launch_bounds__(256) void k2_gemm1_scan1(
        const unsigned short* __restrict__ A, const unsigned short* __restrict__ Bf,
        unsigned short* __restrict__ C, int M, int K,
        const int* __restrict__ deg, int* __restrict__ rowptr, int* __restrict__ bsum) {
    __shared__ int buf[256];
    if (blockIdx.x < GEMM_B) {
        gemm_body(blockIdx.x, threadIdx.x, A, Bf, C, M, K);
    } else {
        int bx = blockIdx.x - GEMM_B;
        int t = threadIdx.x;
        int i = bx * 256 + t;
        int v = (i < NNODES) ? deg[i] : 0;
        buf[t] = v;
        __syncthreads();
        for (int off = 1; off < 256; off <<= 1) {
            int u = (t >= off) ? buf[t - off] : 0;
            __syncthreads();
            buf[t] += u;
            __syncthreads();
        }
        if (i < NNODES) rowptr[i] = buf[t] - v;
        if (t == 255) bsum[bx] = buf[255];
    }
}

// K3: per-block recompute of bsum prefix + add-back (absorbs old scan2)
__global__ __launch_bounds__(256) void k3_scan23(
        const int* __restrict__ bsum, int* __restrict__ rowptr, int* __restrict__ cursor) {
    __shared__ int sbuf[256];
    int t = threadIdx.x;
    int v = (t < (int)blockIdx.x && t < SCAN_B) ? bsum[t] : 0;
    sbuf[t] = v;
    __syncthreads();
    for (int off = 128; off; off >>= 1) {
        if (t < off) sbuf[t] += sbuf[t + off];
        __syncthreads();
    }
    int base = sbuf[0];
    int i = blockIdx.x * 256 + t;
    if (i < NNODES) {
        int r = rowptr[i] + base;
        rowptr[i] = r;
        cursor[i] = r;
    }
    if (blockIdx.x == 0 && t == 0) rowptr[NNODES] = E2;
}

// K4: scatter src into dst-grouped order
__global__ __launch_bounds__(256) void k4_scatter(
        const int* __restrict__ ei, int* __restrict__ cursor, int* __restrict__ csr_src) {
    int i = blockIdx.x * blockDim.x + threadIdx.x;
    if (i >= E2) return;
    int s, d;
    if (i < NEDGES) { s = ei[i]; d = ei[NEDGES + i]; }
    else            { s = i - NEDGES; d = s; }
    int slot = atomicAdd(&cursor[d], 1);
    csr_src[slot] = s;
}

// standalone GEMM (layer 2)
__global__ __launch_bounds__(256) void gemm_mfma(
        const unsigned short* __restrict__ A, const unsigned short* __restrict__ Bf,
        unsigned short* __restrict__ C, int M, int K) {
    gemm_body(blockIdx.x, threadIdx.x, A, Bf, C, M, K);
}

// ---------------- fused per-node GAT: 4 ch/lane, DPP reduce, 4-edge unroll ----------------
// xlr[N][512] bf16: cols 0..255 = xl (messages), 256..511 = xr (dest)
// LAYER==1: out = bf16 h1[N][256] = ELU(BN(agg + b))
// LAYER==2: out = fp32 [N] = sigmoid(fc(ELU(BN(mean_heads(agg) + b))))
template <int LAYER>
__global__ __launch_bounds__(256) void gat_node(
        const unsigned short* __restrict__ xlr,
        const float* __restrict__ att, const int* __restrict__ rowptr,
        const int* __restrict__ csr_src,
        const float* __restrict__ bias, const float* __restrict__ g,
        const float* __restrict__ be,
        const float* __restrict__ fcW, const float* __restrict__ fcb,
        void* __restrict__ outv) {
    int wid  = (blockIdx.x * blockDim.x + threadIdx.x) >> 6;   // node id
    int lane = threadIdx.x & 63;
    if (wid >= NNODES) return;

    f32x2 xb01, xb23, at01, at23;
    {
        uint2 wv = *reinterpret_cast<const uint2*>(xlr + (size_t)wid * NOUT + 256 + lane * 4);
        xb01.x = __uint_as_float(wv.x << 16);
        xb01.y = __uint_as_float(wv.x & 0xffff0000u);
        xb23.x = __uint_as_float(wv.y << 16);
        xb23.y = __uint_as_float(wv.y & 0xffff0000u);
        float4 a = *reinterpret_cast<const float4*>(att + lane * 4);
        at01.x = a.x; at01.y = a.y;
        at23.x = a.z; at23.y = a.w;
    }
    const int beg = rowptr[wid];
    const int end = rowptr[wid + 1];
    const unsigned short* __restrict__ xbase = xlr + lane * 4;

    float den = 0.f;
    f32x2 ac01 = {0.f, 0.f}, ac23 = {0.f, 0.f};

    auto edge = [&](uint2 wv) {
        f32x2 xv01, xv23;
        xv01.x = __uint_as_float(wv.x << 16);
        xv01.y = __uint_as_float(wv.x & 0xffff0000u);
        xv23.x = __uint_as_float(wv.y << 16);
        xv23.y = __uint_as_float(wv.y & 0xffff0000u);
        f32x2 v01 = xv01 + xb01;
        f32x2 v23 = xv23 + xb23;
        v01 = __builtin_elementwise_max(v01, v01 * 0.2f);   // leaky_relu
        v23 = __builtin_elementwise_max(v23, v23 * 0.2f);
        f32x2 d2 = v01 * at01 + v23 * at23;
        float part = row16_sum(d2.x + d2.y);   // per-head logit, VALU DPP only
        // softmax shift-invariant; logits are O(1) -> no max tracking
        float p = __expf(part);
        den += p;
        ac01 += p * xv01;
        ac23 += p * xv23;
    };

    int j = beg;
    for (; j + 4 <= end; j += 4) {
        int s0 = csr_src[j], s1 = csr_src[j + 1], s2 = csr_src[j + 2], s3 = csr_src[j + 3];
        uint2 w0 = *reinterpret_cast<const uint2*>(xbase + (size_t)s0 * NOUT);
        uint2 w1 = *reinterpret_cast<const uint2*>(xbase + (size_t)s1 * NOUT);
        uint2 w2 = *reinterpret_cast<const uint2*>(xbase + (size_t)s2 * NOUT);
        uint2 w3 = *reinterpret_cast<const uint2*>(xbase + (size_t)s3 * NOUT);
        edge(w0); edge(w1); edge(w2); edge(w3);
    }
    for (; j < end; ++j) {
        int s0 = csr_src[j];
        uint2 w0 = *reinterpret_cast<const uint2*>(xbase + (size_t)s0 * NOUT);
        edge(w0);
    }

    float inv = 1.f / (den + 1e-16f);
    float ax = ac01.x * inv, ay = ac01.y * inv, az = ac23.x * inv, aw = ac23.y * inv;

    if (LAYER == 1) {
        int c0 = lane * 4;
        float o0 = (ax + bias[c0 + 0]) * BN_SCALE * g[c0 + 0] + be[c0 + 0];
        float o1 = (ay + bias[c0 + 1]) * BN_SCALE * g[c0 + 1] + be[c0 + 1];
        float o2 = (az + bias[c0 + 2]) * BN_SCALE * g[c0 + 2] + be[c0 + 2];
        float o3 = (aw + bias[c0 + 3]) * BN_SCALE * g[c0 + 3] + be[c0 + 3];
        o0 = o0 > 0.f ? o0 : expm1f(o0);
        o1 = o1 > 0.f ? o1 : expm1f(o1);
        o2 = o2 > 0.f ? o2 : expm1f(o2);
        o3 = o3 > 0.f ? o3 : expm1f(o3);
        ushort4 o = { f2bf(o0), f2bf(o1), f2bf(o2), f2bf(o3) };
        *reinterpret_cast<ushort4*>((unsigned short*)outv + (size_t)wid * HC + lane * 4) = o;
    } else {
        // mean over heads: lanes l, l^16, l^32, l^48 hold the same channels
#pragma unroll
        for (int off = 16; off < 64; off <<= 1) {
            ax += __shfl_xor(ax, off);
            ay += __shfl_xor(ay, off);
            az += __shfl_xor(az, off);
            aw += __shfl_xor(aw, off);
        }
        int c0 = (lane & 15) * 4;
        float v0 = (ax * 0.25f + bias[c0 + 0]) * BN_SCALE * g[c0 + 0] + be[c0 + 0];
        float v1 = (ay * 0.25f + bias[c0 + 1]) * BN_SCALE * g[c0 + 1] + be[c0 + 1];
        float v2 = (az * 0.25f + bias[c0 + 2]) * BN_SCALE * g[c0 + 2] + be[c0 + 2];
        float v3 = (aw * 0.25f + bias[c0 + 3]) * BN_SCALE * g[c0 + 3] + be[c0 + 3];
        v0 = v0 > 0.f ? v0 : expm1f(v0);
        v1 = v1 > 0.f ? v1 : expm1f(v1);
        v2 = v2 > 0.f ? v2 : expm1f(v2);
        v3 = v3 > 0.f ? v3 : expm1f(v3);
        float dot = v0 * fcW[c0] + v1 * fcW[c0 + 1] + v2 * fcW[c0 + 2] + v3 * fcW[c0 + 3];
        dot = row16_sum(dot);
        if (lane == 0) ((float*)outv)[wid] = 1.f / (1.f + __expf(-(dot + fcb[0])));
    }
}

extern "C" void kernel_launch(void* const* d_in, const int* in_sizes, int n_in,
                              void* d_out, int out_size, void* d_ws, size_t ws_size,
                              hipStream_t stream) {
    const float* x    = (const float*)d_in[0];
    const int*   ei   = (const int*)d_in[1];
    const float* W1l  = (const float*)d_in[2];
    const float* W1r  = (const float*)d_in[3];
    const float* att1 = (const float*)d_in[4];
    const float* b1   = (const float*)d_in[5];
    const float* g1   = (const float*)d_in[6];
    const float* be1  = (const float*)d_in[7];
    const float* W2l  = (const float*)d_in[8];
    const float* W2r  = (const float*)d_in[9];
    const float* att2 = (const float*)d_in[10];
    const float* b2   = (const float*)d_in[11];
    const float* g2   = (const float*)d_in[12];
    const float* be2  = (const float*)d_in[13];
    const float* fcW  = (const float*)d_in[14];
    const float* fcb  = (const float*)d_in[15];
    float* out = (float*)d_out;

    // workspace carve-up (bf16 = ushort)
    unsigned short* xlr   = (unsigned short*)d_ws;                 // N*512
    unsigned short* x_bf  = xlr + (size_t)NNODES * NOUT;           // N*128
    unsigned short* h1_bf = x_bf + (size_t)NNODES * 128;           // N*256
    unsigned short* Bf1   = h1_bf + (size_t)NNODES * 256;          // 128*512
    unsigned short* Bf2   = Bf1 + 128 * NOUT;                      // 256*512
    int* csr_src = (int*)(Bf2 + 256 * NOUT);                       // E2
    int* deg     = csr_src + E2;                                   // N
    int* rowptr  = deg + NNODES;                                   // N+1
    int* cursor  = rowptr + NNODES + 1;                            // N
    int* bsum    = cursor + NNODES;                                // SCAN_B

    const int nodeBlocks = (NNODES * 64 + 255) / 256;

    hipMemsetAsync(deg, 0, NNODES * sizeof(int), stream);

    // K1: pack (x, W1, W2) || dst histogram
    k1_pack_hist<<<PACK_B + HIST_B, 256, 0, stream>>>(
        x, W1l, W1r, W2l, W2r, x_bf, Bf1, Bf2, ei, deg);

    // K2: gemm layer-1 || scan1
    k2_gemm1_scan1<<<GEMM_B + SCAN_B, 256, 0, stream>>>(
        x_bf, Bf1, xlr, NNODES, 128, deg, rowptr, bsum);

    // K3: bsum prefix + add-back
    k3_scan23<<<SCAN_B, 256, 0, stream>>>(bsum, rowptr, cursor);

    // K4: scatter into CSR
    k4_scatter<<<HIST_B, 256, 0, stream>>>(ei, cursor, csr_src);

    // layer 1 aggregation + epilogue
    gat_node<1><<<nodeBlocks, 256, 0, stream>>>(xlr, att1, rowptr, csr_src,
                                                b1, g1, be1, nullptr, nullptr, h1_bf);

    // layer 2
    gemm_mfma<<<GEMM_B, 256, 0, stream>>>(h1_bf, Bf2, xlr, NNODES, 256);
    gat_node<2><<<nodeBlocks, 256, 0, stream>>>(xlr, att2, rowptr, csr_src,
                                                b2, g2, be2, fcW, fcb, out);
}